// Round 1
// baseline (134.798 us; speedup 1.0000x reference)
//
#include <hip/hip_runtime.h>

// Problem constants
// B=128, IN_F=256, HID=512, OUT=128, E=8
//
// Workspace layout (float offsets):
//   A   [E][IN_F][HID]      @ 0         size 1048576   A = 1 - w*s
//   Bm  [E][IN_F][HID]      @ 1048576   size 1048576   Bm = w*(2s-1)
//   xT  [E][IN_F][B]        @ 2097152   size 262144
//   dwT [E][OUT][HID]       @ 2359296   size 524288
//   P   [4][E][B][HID]      @ 2883584   size 2097152   stage-1 partial products
//   H   [E][B][HID]         @ 4980736   size 524288
// total 5505024 floats = 21.0 MB of ws

#define OFF_A   0
#define OFF_B   1048576
#define OFF_X   2097152
#define OFF_D   2359296
#define OFF_P   2883584
#define OFF_H   4980736

// ---------------------------------------------------------------------------
// Prep: build transposed operand tables.
//  blocks [0,256)   : per-i transpose of conj_weights/conj_signs -> A,Bm [e][i][h]
//  blocks [256,512) : per-i transpose of input -> xT [e][i][b]
//  blocks [512,640) : per-o transpose of disj_weights -> dwT [e][o][h]
// ---------------------------------------------------------------------------
__global__ __launch_bounds__(256) void k_prep(const float* __restrict__ in,
                                              const float* __restrict__ cw,
                                              const float* __restrict__ cs,
                                              const float* __restrict__ dw,
                                              float* __restrict__ ws)
{
    __shared__ float lds[8320];          // 2 x 8 x 520 floats = 33.3 KB max
    const int tid = threadIdx.x;
    const int blk = blockIdx.x;
    float* WA = ws + OFF_A;
    float* WB = ws + OFF_B;
    float* WX = ws + OFF_X;
    float* WD = ws + OFF_D;

    if (blk < 256) {
        // A/Bm: read cw[i][:][:], cs[i][:][:] (4096 floats each, contiguous)
        const int i = blk;
        const float4* cw4 = (const float4*)(cw + i * 4096);
        const float4* cs4 = (const float4*)(cs + i * 4096);
        float* ldsA = lds;
        float* ldsB = lds + 4160;
        #pragma unroll
        for (int k = 0; k < 4; ++k) {
            const int idx = tid + k * 256;
            const float4 w4 = cw4[idx];
            const float4 s4 = cs4[idx];
            const float wv[4] = {w4.x, w4.y, w4.z, w4.w};
            const float sv[4] = {s4.x, s4.y, s4.z, s4.w};
            #pragma unroll
            for (int j = 0; j < 4; ++j) {
                const int f = idx * 4 + j;
                const int h = f >> 3, e = f & 7;
                ldsA[e * 520 + h] = 1.0f - wv[j] * sv[j];
                ldsB[e * 520 + h] = wv[j] * (2.0f * sv[j] - 1.0f);
            }
        }
        __syncthreads();
        #pragma unroll
        for (int e = 0; e < 8; ++e) {
            #pragma unroll
            for (int k = 0; k < 2; ++k) {
                const int h = tid + k * 256;
                const int off = (e * 256 + i) * 512 + h;
                WA[off] = ldsA[e * 520 + h];
                WB[off] = ldsB[e * 520 + h];
            }
        }
    } else if (blk < 512) {
        // xT[e][i][b] from input[b][i][e]
        const int i = blk - 256;
        #pragma unroll
        for (int k = 0; k < 4; ++k) {
            const int f = tid + k * 256;          // 0..1023
            const int b = f >> 3, e = f & 7;
            lds[e * 136 + b] = in[b * 2048 + i * 8 + e];
        }
        __syncthreads();
        #pragma unroll
        for (int k = 0; k < 4; ++k) {
            const int f = tid + k * 256;
            const int e = f >> 7, b = f & 127;
            WX[(e * 256 + i) * 128 + b] = lds[e * 136 + b];
        }
    } else {
        // dwT[e][o][h] from dw[h][o][e]
        const int o = blk - 512;
        #pragma unroll
        for (int k = 0; k < 16; ++k) {
            const int f = tid + k * 256;          // 0..4095
            const int h = f >> 3, e = f & 7;
            lds[e * 520 + h] = dw[h * 1024 + o * 8 + e];
        }
        __syncthreads();
        #pragma unroll
        for (int k = 0; k < 16; ++k) {
            const int f = tid + k * 256;
            const int e = f >> 9, h = f & 511;
            WD[(e * 128 + o) * 512 + h] = lds[e * 520 + h];
        }
    }
}

// ---------------------------------------------------------------------------
// Stage 1 (K-split x4): P[c][e][b][h] = prod_{i in chunk c} (A[e][i][h] + x[e][i][b]*Bm[e][i][h])
// Thread micro-tile: 8 b x 4 h. 65536 threads (256 blocks).
// Lanes map to consecutive h-quads -> coalesced float4 A/B loads; x loads wave-uniform.
// ---------------------------------------------------------------------------
__global__ __launch_bounds__(256) void k_s1(float* __restrict__ ws)
{
    const float* WA = ws + OFF_A;
    const float* WB = ws + OFF_B;
    const float* WX = ws + OFF_X;
    float* WP = ws + OFF_P;

    const int gid = blockIdx.x * 256 + threadIdx.x;
    const int hq = gid & 127;          // 128 h-quads
    const int bp = (gid >> 7) & 15;    // 16 b-octets
    const int e  = (gid >> 11) & 7;
    const int c  = gid >> 14;          // 4 K-chunks
    const int h0 = hq * 4;
    const int b0 = bp * 8;
    const int ibase = c * 64;

    const float* pA = WA + e * 131072 + ibase * 512 + h0;
    const float* pB = WB + e * 131072 + ibase * 512 + h0;
    const float* pX = WX + e * 32768 + ibase * 128 + b0;

    float acc[8][4];
    #pragma unroll
    for (int j = 0; j < 8; ++j)
        #pragma unroll
        for (int k = 0; k < 4; ++k) acc[j][k] = 1.0f;

    #pragma unroll 4
    for (int ii = 0; ii < 64; ++ii) {
        const float4 a4 = *(const float4*)pA;
        const float4 m4 = *(const float4*)pB;
        const float4 xa = *(const float4*)pX;
        const float4 xb = *(const float4*)(pX + 4);
        pA += 512; pB += 512; pX += 128;
        const float xs[8] = {xa.x, xa.y, xa.z, xa.w, xb.x, xb.y, xb.z, xb.w};
        #pragma unroll
        for (int j = 0; j < 8; ++j) {
            acc[j][0] *= fmaf(xs[j], m4.x, a4.x);
            acc[j][1] *= fmaf(xs[j], m4.y, a4.y);
            acc[j][2] *= fmaf(xs[j], m4.z, a4.z);
            acc[j][3] *= fmaf(xs[j], m4.w, a4.w);
        }
    }

    float* pO = WP + ((c * 8 + e) * 128 + b0) * 512 + h0;
    #pragma unroll
    for (int j = 0; j < 8; ++j) {
        float4 v = {acc[j][0], acc[j][1], acc[j][2], acc[j][3]};
        *(float4*)(pO + j * 512) = v;
    }
}

// ---------------------------------------------------------------------------
// Combine stage-1 partials: H = P0*P1*P2*P3 (elementwise over [e][b][h])
// ---------------------------------------------------------------------------
__global__ __launch_bounds__(256) void k_comb1(float* __restrict__ ws)
{
    const float* WP = ws + OFF_P;
    float* WH = ws + OFF_H;
    const int idx4 = blockIdx.x * 256 + threadIdx.x;   // 131072 float4s
    const float4 p0 = *(const float4*)(WP + 0 * 524288 + idx4 * 4);
    const float4 p1 = *(const float4*)(WP + 1 * 524288 + idx4 * 4);
    const float4 p2 = *(const float4*)(WP + 2 * 524288 + idx4 * 4);
    const float4 p3 = *(const float4*)(WP + 3 * 524288 + idx4 * 4);
    float4 r;
    r.x = p0.x * p1.x * p2.x * p3.x;
    r.y = p0.y * p1.y * p2.y * p3.y;
    r.z = p0.z * p1.z * p2.z * p3.z;
    r.w = p0.w * p1.w * p2.w * p3.w;
    *(float4*)(WH + idx4 * 4) = r;
}

// ---------------------------------------------------------------------------
// Stage 2: out[b][o][e] = 1 - prod_h (1 - dwT[e][o][h] * H[e][b][h])
// Thread: 2 o-values for fixed (b,e), full h loop. 65536 threads (256 blocks).
// H loads wave-uniform; dwT rows lane-varying but L1-line-reused 8x along h.
// ---------------------------------------------------------------------------
__global__ __launch_bounds__(256) void k_s2(const float* __restrict__ ws,
                                            float* __restrict__ out)
{
    const float* WD = ws + OFF_D;
    const float* WH = ws + OFF_H;
    const int gid = blockIdx.x * 256 + threadIdx.x;
    const int op = gid & 63;           // 64 o-pairs
    const int b  = (gid >> 6) & 127;
    const int e  = gid >> 13;
    const int o0 = op * 2;

    const float* pH = WH + (e * 128 + b) * 512;
    const float* pD0 = WD + (e * 128 + o0) * 512;
    const float* pD1 = pD0 + 512;

    float acc0 = 1.0f, acc1 = 1.0f;
    #pragma unroll 4
    for (int h = 0; h < 512; h += 4) {
        const float4 H4 = *(const float4*)(pH + h);
        const float4 d0 = *(const float4*)(pD0 + h);
        const float4 d1 = *(const float4*)(pD1 + h);
        acc0 *= fmaf(-d0.x, H4.x, 1.0f);
        acc0 *= fmaf(-d0.y, H4.y, 1.0f);
        acc0 *= fmaf(-d0.z, H4.z, 1.0f);
        acc0 *= fmaf(-d0.w, H4.w, 1.0f);
        acc1 *= fmaf(-d1.x, H4.x, 1.0f);
        acc1 *= fmaf(-d1.y, H4.y, 1.0f);
        acc1 *= fmaf(-d1.z, H4.z, 1.0f);
        acc1 *= fmaf(-d1.w, H4.w, 1.0f);
    }
    out[(b * 128 + o0) * 8 + e]     = 1.0f - acc0;
    out[(b * 128 + o0 + 1) * 8 + e] = 1.0f - acc1;
}

extern "C" void kernel_launch(void* const* d_in, const int* in_sizes, int n_in,
                              void* d_out, int out_size, void* d_ws, size_t ws_size,
                              hipStream_t stream)
{
    const float* in = (const float*)d_in[0];   // [128][256][8]
    const float* cw = (const float*)d_in[1];   // [256][512][8]
    const float* cs = (const float*)d_in[2];   // [256][512][8]
    const float* dw = (const float*)d_in[3];   // [512][128][8]
    float* out = (float*)d_out;                // [128][128][8]
    float* ws = (float*)d_ws;                  // needs 22,020,096 bytes

    k_prep<<<640, 256, 0, stream>>>(in, cw, cs, dw, ws);
    k_s1<<<256, 256, 0, stream>>>(ws);
    k_comb1<<<512, 256, 0, stream>>>(ws);
    k_s2<<<256, 256, 0, stream>>>(ws, out);
}

// Round 2
// 110.430 us; speedup vs baseline: 1.2207x; 1.2207x over previous
//
#include <hip/hip_runtime.h>

// EmbedDNF: B=128, IN_F=256, HID=512, OUT=128, E=8 (all fp32, e innermost)
//
// Math: xnor = x*s + (1-x)(1-s); impl = 1 - w*(1-xnor) = A + x*Bv
//       with A = 1 - w*s, Bv = 2*w*s - w  (verified: s=1 -> 1-w+wx... full check
//       A + xB = 1 - ws + x(2ws - w) = 1 - w(1 - (1 - s - x + 2xs)) ✓)
// H[b,h,e] = prod_i impl ; out[b,o,e] = 1 - prod_h (1 - dw[h,o,e]*H[b,h,e])
//
// ws layout: H [128][512][8] fp32 @ float offset 0 (2 MB)

// ---------------------------------------------------------------------------
// Stage 1: grid 1024 = 16 b-groups(8 b) x 64 h-groups(8 h); block 128 thr =
// 8 h-lanes x 16 i-chunks(16 i). Thread tile: 8 b x 8 e x 1 h. A/Bv computed
// on the fly from raw cw/cs (contiguous 32 B loads, no transpose). Partial
// products over i combined in-block via LDS.
// ---------------------------------------------------------------------------
__global__ __launch_bounds__(128, 2) void k_stage1(
    const float* __restrict__ in,   // [128][256][8]
    const float* __restrict__ cw,   // [256][512][8]
    const float* __restrict__ cs,   // [256][512][8]
    float* __restrict__ Hout)       // ws: [128][512][8]
{
    __shared__ float lds[8192];     // [8 hl][8 b][8 e][16 ck] = 32 KB
    const int t  = threadIdx.x;
    const int hl = t & 7;
    const int ck = t >> 3;          // 16 chunks of 16 i
    const int hg = blockIdx.x & 63; // h-group in LOW bits -> per-XCD w/s slice ~1MB
    const int bp = blockIdx.x >> 6;
    const int h  = hg * 8 + hl;
    const int b0 = bp * 8;

    float acc[8][8];
    #pragma unroll
    for (int b = 0; b < 8; ++b)
        #pragma unroll
        for (int e = 0; e < 8; ++e) acc[b][e] = 1.0f;

    const float* pw = cw + (ck * 16) * 4096 + h * 8;
    const float* ps = cs + (ck * 16) * 4096 + h * 8;
    const float* px = in + b0 * 2048 + (ck * 16) * 8;

    #pragma unroll 2
    for (int ii = 0; ii < 16; ++ii) {
        float wv[8], sv[8], Av[8], Bv[8];
        *(float4*)(wv)     = *(const float4*)(pw);
        *(float4*)(wv + 4) = *(const float4*)(pw + 4);
        *(float4*)(sv)     = *(const float4*)(ps);
        *(float4*)(sv + 4) = *(const float4*)(ps + 4);
        pw += 4096; ps += 4096;
        #pragma unroll
        for (int e = 0; e < 8; ++e) {
            const float p = wv[e] * sv[e];
            Av[e] = 1.0f - p;
            Bv[e] = fmaf(2.0f, p, -wv[e]);
        }
        #pragma unroll
        for (int b = 0; b < 8; ++b) {
            float xv[8];
            *(float4*)(xv)     = *(const float4*)(px + b * 2048);
            *(float4*)(xv + 4) = *(const float4*)(px + b * 2048 + 4);
            #pragma unroll
            for (int e = 0; e < 8; ++e)
                acc[b][e] *= fmaf(xv[e], Bv[e], Av[e]);
        }
        px += 8;
    }

    // in-block combine over 16 i-chunks
    #pragma unroll
    for (int b = 0; b < 8; ++b)
        #pragma unroll
        for (int e = 0; e < 8; ++e)
            lds[((hl * 64 + b * 8 + e) << 4) + ck] = acc[b][e];
    __syncthreads();

    // 512 outputs (hl,b,e), 128 threads -> 4 each (an e-quad: (4t)&7 in {0,4})
    const int oid = t * 4;
    const int hlo = oid >> 6, bo = (oid >> 3) & 7, e0 = oid & 7;
    float4 r;
    float* pr = &r.x;
    #pragma unroll
    for (int j = 0; j < 4; ++j) {
        const float* q = &lds[((hlo * 64 + bo * 8 + e0 + j) << 4)];
        float m = 1.0f;
        #pragma unroll
        for (int c = 0; c < 16; ++c) m *= q[c];
        pr[j] = m;
    }
    *(float4*)(Hout + (b0 + bo) * 4096 + (hg * 8 + hlo) * 8 + e0) = r;
}

// ---------------------------------------------------------------------------
// Stage 2: grid 256 = 64 b-pairs x 4 o-groups(32 o); block 512 thr =
// 32 o-lanes x 16 h-chunks(32 h). Thread tile: 2 b x 8 e x 1 o.
// dw loads: 32 consecutive o-lanes x 32 B = 1 KB contiguous. H loads
// wave-quasi-uniform (2 addresses/wave). In-block LDS combine over h-chunks.
// ---------------------------------------------------------------------------
__global__ __launch_bounds__(512, 4) void k_stage2(
    const float* __restrict__ dw,   // [512][128][8]
    const float* __restrict__ H,    // ws: [128][512][8]
    float* __restrict__ out)        // [128][128][8]
{
    __shared__ float lds[8736];     // [32 ol][(bb*8+e)*17 + hc], 273/ol, pad kills conflicts
    const int t  = threadIdx.x;
    const int ol = t & 31;
    const int hc = t >> 5;          // 16 chunks of 32 h
    const int og = blockIdx.x & 3;
    const int bg = blockIdx.x >> 2;
    const int o  = og * 32 + ol;
    const int b0 = bg * 2;

    float acc[2][8];
    #pragma unroll
    for (int bb = 0; bb < 2; ++bb)
        #pragma unroll
        for (int e = 0; e < 8; ++e) acc[bb][e] = 1.0f;

    const float* pd = dw + (hc * 32) * 1024 + o * 8;
    const float* ph = H + b0 * 4096 + (hc * 32) * 8;

    #pragma unroll 2
    for (int ii = 0; ii < 32; ++ii) {
        float dv[8];
        *(float4*)(dv)     = *(const float4*)(pd);
        *(float4*)(dv + 4) = *(const float4*)(pd + 4);
        pd += 1024;
        #pragma unroll
        for (int bb = 0; bb < 2; ++bb) {
            float hv[8];
            *(float4*)(hv)     = *(const float4*)(ph + bb * 4096);
            *(float4*)(hv + 4) = *(const float4*)(ph + bb * 4096 + 4);
            #pragma unroll
            for (int e = 0; e < 8; ++e)
                acc[bb][e] *= fmaf(-dv[e], hv[e], 1.0f);
        }
        ph += 8;
    }

    #pragma unroll
    for (int bb = 0; bb < 2; ++bb)
        #pragma unroll
        for (int e = 0; e < 8; ++e)
            lds[ol * 273 + (bb * 8 + e) * 17 + hc] = acc[bb][e];
    __syncthreads();

    // 512 outputs, 512 threads -> 1 each
    const int eo = t & 7, bo = (t >> 3) & 1, olo = t >> 4;
    const float* q = &lds[olo * 273 + (bo * 8 + eo) * 17];
    float m = 1.0f;
    #pragma unroll
    for (int c = 0; c < 16; ++c) m *= q[c];
    out[(b0 + bo) * 1024 + (og * 32 + olo) * 8 + eo] = 1.0f - m;
}

extern "C" void kernel_launch(void* const* d_in, const int* in_sizes, int n_in,
                              void* d_out, int out_size, void* d_ws, size_t ws_size,
                              hipStream_t stream)
{
    const float* in = (const float*)d_in[0];   // [128][256][8]
    const float* cw = (const float*)d_in[1];   // [256][512][8]
    const float* cs = (const float*)d_in[2];   // [256][512][8]
    const float* dw = (const float*)d_in[3];   // [512][128][8]
    float* out = (float*)d_out;                // [128][128][8]
    float* H   = (float*)d_ws;                 // 2 MB used

    k_stage1<<<1024, 128, 0, stream>>>(in, cw, cs, H);
    k_stage2<<<256, 512, 0, stream>>>(dw, H, out);
}